// Round 11
// baseline (65.848 us; speedup 1.0000x reference)
//
#include <hip/hip_runtime.h>
#include <math.h>

// FFT circular conv: y[b,h,:] = irfft(rfft(x[b,h,:]) * rfft(k[h,:])), N=4096.
// M=2048 complex FFT via even/odd packing. Stockham radix 8,8,8,4.
// LDS layout engineered for ds_read2/write2 merging (round 10). This round:
// twiddle VALU trim — direct v_sin/v_cos in REVOLUTIONS (angles k/2048,
// k/4096 are exact and pre-reduced; skips __sincosf range reduction), and
// fwd4_pw shares one sincos across its 4 conjugate pairs via pi/4-rotation
// identities (t==0: all-constant). VGPR kept <=64 (no persistent hoists).

#define NT 256
#define KF_LD 2049
#define C_SQRT1_2 0.70710678118654752f
#define C_COS_PI8 0.92387953251128675f
#define C_SIN_PI8 0.38268343236508977f
#define INV_2048 4.8828125e-4f
#define INV_4096 2.44140625e-4f

// Word swizzle (bijective involution on [0,2048), keyed on bits>=5).
#define SW(a) ((a) ^ (((a) >> 5) & 31) ^ (((a) >> 2) & 24))
// Point index -> LDS word index of re part (im at +64).
__device__ __forceinline__ int WP(int a) {
  const int s = SW(a);
  return 2 * s - (s & 63);
}

// sn = sin(2*pi*f), cs = cos(2*pi*f); f MUST be in [0,1) (pre-reduced).
__device__ __forceinline__ void sincos_rev(float f, float& sn, float& cs) {
  float s_, c_;
  asm("v_sin_f32 %0, %1" : "=v"(s_) : "v"(f));
  asm("v_cos_f32 %0, %1" : "=v"(c_) : "v"(f));
  sn = s_; cs = c_;
}

template <int SIGN>
__device__ __forceinline__ void bf8(const float ar[8], const float ai[8],
                                    float br[8], float bi[8]) {
  float s0r = ar[0] + ar[4], s0i = ai[0] + ai[4];
  float s1r = ar[0] - ar[4], s1i = ai[0] - ai[4];
  float s2r = ar[2] + ar[6], s2i = ai[2] + ai[6];
  float s3r = ar[2] - ar[6], s3i = ai[2] - ai[6];
  float E0r = s0r + s2r, E0i = s0i + s2i;
  float E2r = s0r - s2r, E2i = s0i - s2i;
  float E1r, E1i, E3r, E3i;
  if (SIGN < 0) { E1r = s1r + s3i; E1i = s1i - s3r; E3r = s1r - s3i; E3i = s1i + s3r; }
  else          { E1r = s1r - s3i; E1i = s1i + s3r; E3r = s1r + s3i; E3i = s1i - s3r; }
  float u0r = ar[1] + ar[5], u0i = ai[1] + ai[5];
  float u1r = ar[1] - ar[5], u1i = ai[1] - ai[5];
  float u2r = ar[3] + ar[7], u2i = ai[3] + ai[7];
  float u3r = ar[3] - ar[7], u3i = ai[3] - ai[7];
  float O0r = u0r + u2r, O0i = u0i + u2i;
  float O2r = u0r - u2r, O2i = u0i - u2i;
  float O1r, O1i, O3r, O3i;
  if (SIGN < 0) { O1r = u1r + u3i; O1i = u1i - u3r; O3r = u1r - u3i; O3i = u1i + u3r; }
  else          { O1r = u1r - u3i; O1i = u1i + u3r; O3r = u1r + u3i; O3i = u1i - u3r; }
  float t1r, t1i, t2r, t2i, t3r, t3i;
  if (SIGN < 0) {
    t1r = C_SQRT1_2 * (O1r + O1i); t1i = C_SQRT1_2 * (O1i - O1r);
    t2r = O2i;  t2i = -O2r;
    t3r = C_SQRT1_2 * (O3i - O3r); t3i = -C_SQRT1_2 * (O3r + O3i);
  } else {
    t1r = C_SQRT1_2 * (O1r - O1i); t1i = C_SQRT1_2 * (O1i + O1r);
    t2r = -O2i; t2i = O2r;
    t3r = -C_SQRT1_2 * (O3r + O3i); t3i = C_SQRT1_2 * (O3r - O3i);
  }
  br[0] = E0r + O0r; bi[0] = E0i + O0i;
  br[4] = E0r - O0r; bi[4] = E0i - O0i;
  br[1] = E1r + t1r; bi[1] = E1i + t1i;
  br[5] = E1r - t1r; bi[5] = E1i - t1i;
  br[2] = E2r + t2r; bi[2] = E2i + t2i;
  br[6] = E2r - t2r; bi[6] = E2i - t2i;
  br[3] = E3r + t3r; bi[3] = E3i + t3i;
  br[7] = E3r - t3r; bi[7] = E3i - t3i;
}

// Twiddled scatter-write: Y[ob+S*m] = b[m] * w^m, w = e^{SIGN*2*pi*i*f1}.
// Serial power chain (one live pair -> minimal VGPR). f1 in revolutions.
template <int SIGN, int S>
__device__ __forceinline__ void tw_write(float* Y, int ob,
                                         const float br[8], const float bi[8],
                                         float f1) {
  { const int i0 = WP(ob); Y[i0] = br[0]; Y[i0 + 64] = bi[0]; }
  float sn, cs;
  sincos_rev(f1, sn, cs);
  const float w1r = cs, w1i = (SIGN > 0) ? sn : -sn;
  float cwr = w1r, cwi = w1i;
#pragma unroll
  for (int m = 1; m < 8; ++m) {
    const int idx = WP(ob + S * m);
    Y[idx] = br[m] * cwr - bi[m] * cwi;
    Y[idx + 64] = br[m] * cwi + bi[m] * cwr;
    if (m < 7) {
      const float nr = cwr * w1r - cwi * w1i;
      const float ni = cwr * w1i + cwi * w1r;
      cwr = nr; cwi = ni;
    }
  }
}

// Out-of-place Stockham radix-8 stage. No internal barrier.
template <int SIGN, int S>
__device__ __forceinline__ void stage_r8(const float* X, float* Y,
                                         const int rd[8]) {
  const int t = (int)threadIdx.x;
  const int q = t & (S - 1);
  const int p = t / S;
  float ar[8], ai[8];
#pragma unroll
  for (int j = 0; j < 8; ++j) {
    ar[j] = X[rd[j]];
    ai[j] = X[rd[j] + 64];
  }
  float br[8], bi[8];
  bf8<SIGN>(ar, ai, br, bi);
  tw_write<SIGN, S>(Y, q + 8 * S * p, br, bi, (float)(S * p) * INV_2048);
}

// Stage 1 (S=1) fused with the global load (src = packed complex row).
template <int SIGN>
__device__ __forceinline__ void stage1_global(const float2* __restrict__ src,
                                              float* Y) {
  const int t = (int)threadIdx.x;
  float ar[8], ai[8];
#pragma unroll
  for (int j = 0; j < 8; ++j) {
    const float2 v = src[t + 256 * j];
    ar[j] = v.x; ai[j] = v.y;
  }
  float br[8], bi[8];
  bf8<SIGN>(ar, ai, br, bi);
  tw_write<SIGN, 1>(Y, 8 * t, br, bi, (float)t * INV_2048);
}

// Forward radix-4 final-stage butterfly (twiddle-free), reads X at base b.
__device__ __forceinline__ void bf4f(const float* X, int b,
                                     float orr[4], float oi[4]) {
  const int i0 = WP(b), i1 = WP(b + 512), i2 = WP(b + 1024), i3 = WP(b + 1536);
  float a0r = X[i0], a0i = X[i0 + 64];
  float a1r = X[i1], a1i = X[i1 + 64];
  float a2r = X[i2], a2i = X[i2 + 64];
  float a3r = X[i3], a3i = X[i3 + 64];
  float s0r = a0r + a2r, s0i = a0i + a2i;
  float s1r = a0r - a2r, s1i = a0i - a2i;
  float s2r = a1r + a3r, s2i = a1i + a3i;
  float s3r = a1r - a3r, s3i = a1i - a3i;
  orr[0] = s0r + s2r; oi[0] = s0i + s2i;
  orr[1] = s1r + s3i; oi[1] = s1i - s3r;
  orr[2] = s0r - s2r; oi[2] = s0i - s2i;
  orr[3] = s1r - s3i; oi[3] = s1i + s3r;
}

// rfft-unpack of conjugate pair (klo, 2048-klo), multiply by kf, repack.
// (cs, sn) = utw(klo) = (cos, sin)(2*pi*klo/4096), supplied by caller.
__device__ __forceinline__ void pw_pair(int klo, float Pr, float Pi, float Qr,
                                        float Qi, const float2* __restrict__ kfrow,
                                        float cs, float sn,
                                        float2& zlo, float2& zhi) {
  const float Er = 0.5f * (Pr + Qr), Ei = 0.5f * (Pi - Qi);
  const float Or = 0.5f * (Pi + Qi), Oi = 0.5f * (Qr - Pr);
  const float Xpr = Er + cs * Or + sn * Oi, Xpi = Ei + cs * Oi - sn * Or;
  const float Xqr = Er - cs * Or - sn * Oi, Xqi = -Ei + cs * Oi - sn * Or;
  const float2 Kp = kfrow[klo];
  const float2 Kq = kfrow[2048 - klo];
  const float Ypr = Xpr * Kp.x - Xpi * Kp.y, Ypi = Xpr * Kp.y + Xpi * Kp.x;
  const float Yqr = Xqr * Kq.x - Xqi * Kq.y, Yqi = Xqr * Kq.y + Xqi * Kq.x;
  const float Epr = 0.5f * (Ypr + Yqr), Epi = 0.5f * (Ypi - Yqi);
  const float Dr = 0.5f * (Ypr - Yqr), Di = 0.5f * (Ypi + Yqi);
  zlo = make_float2(Epr - cs * Di - sn * Dr, Epi + cs * Dr - sn * Di);
  zhi = make_float2(Epr + cs * Di + sn * Dr, -Epi + cs * Dr - sn * Di);
}

// Forward final radix-4 stage fused with unpack * kf * repack, out-of-place.
// Thread t does butterflies t and 512-t (t=0: 0 and 256): their 8 outputs
// form exactly the conjugate pairs (kk, 2048-kk). One sincos serves all 4
// pairs via pi/4-rotation identities; t==0 is all-constant.
__device__ __forceinline__ void fwd4_pw(const float* X, float* Y,
                                        const float2* __restrict__ kfrow) {
  const int t = (int)threadIdx.x;
  const int b1 = (t == 0) ? 256 : 512 - t;
  float Ar[4], Ai[4], Br[4], Bi[4];
  bf4f(X, t, Ar, Ai);
  bf4f(X, b1, Br, Bi);
  int k0, k1, k2, k3;
  float2 zl0, zh0, zl1, zh1, zl2, zh2, zl3, zh3, zl4;
  zl4 = make_float2(0.f, 0.f);
  if (t == 0) {
    float2 zh4;
    k0 = 0;   pw_pair(0,   Ar[0], Ai[0], Ar[0], Ai[0], kfrow, 1.0f, 0.0f, zl0, zh0);
    k1 = 512; pw_pair(512, Ar[1], Ai[1], Ar[3], Ai[3], kfrow, C_SQRT1_2, C_SQRT1_2, zl1, zh1);
    k2 = 256; pw_pair(256, Br[0], Bi[0], Br[3], Bi[3], kfrow, C_COS_PI8, C_SIN_PI8, zl2, zh2);
    k3 = 768; pw_pair(768, Br[1], Bi[1], Br[2], Bi[2], kfrow, C_SIN_PI8, C_COS_PI8, zl3, zh3);
    pw_pair(1024, Ar[2], Ai[2], Ar[2], Ai[2], kfrow, 0.0f, 1.0f, zl4, zh4);
  } else {
    float s, c;
    sincos_rev((float)t * INV_4096, s, c);           // utw(t)
    const float pr = C_SQRT1_2 * (c - s);            // cos(t + pi/4-rot terms)
    const float ps = C_SQRT1_2 * (c + s);
    k0 = t;        pw_pair(k0, Ar[0], Ai[0], Br[3], Bi[3], kfrow, c, s, zl0, zh0);
    k1 = t + 512;  pw_pair(k1, Ar[1], Ai[1], Br[2], Bi[2], kfrow, pr, ps, zl1, zh1);
    k2 = 1024 - t; pw_pair(k2, Br[1], Bi[1], Ar[2], Ai[2], kfrow, s, c, zl2, zh2);
    k3 = 512 - t;  pw_pair(k3, Br[0], Bi[0], Ar[3], Ai[3], kfrow, ps, pr, zl3, zh3);
  }
  {
    int i;
    i = WP(k0);                 Y[i] = zl0.x; Y[i + 64] = zl0.y;
    i = WP((2048 - k0) & 2047); Y[i] = zh0.x; Y[i + 64] = zh0.y;
    i = WP(k1);                 Y[i] = zl1.x; Y[i + 64] = zl1.y;
    i = WP(2048 - k1);          Y[i] = zh1.x; Y[i + 64] = zh1.y;
    i = WP(k2);                 Y[i] = zl2.x; Y[i + 64] = zl2.y;
    i = WP(2048 - k2);          Y[i] = zh2.x; Y[i + 64] = zh2.y;
    i = WP(k3);                 Y[i] = zl3.x; Y[i + 64] = zl3.y;
    i = WP(2048 - k3);          Y[i] = zh3.x; Y[i + 64] = zh3.y;
    if (t == 0) { i = WP(1024); Y[i] = zl4.x; Y[i + 64] = zl4.y; }
  }
}

// Inverse final radix-4 stage (twiddle-free) fused with the global store.
__device__ __forceinline__ void inv4_store(const float* X,
                                           float2* __restrict__ dst) {
  const int t = (int)threadIdx.x;
#pragma unroll
  for (int c = 0; c < 2; ++c) {
    const int b = t + 256 * c;
    const int i0 = WP(b), i1 = WP(b + 512), i2 = WP(b + 1024), i3 = WP(b + 1536);
    float a0r = X[i0], a0i = X[i0 + 64];
    float a1r = X[i1], a1i = X[i1 + 64];
    float a2r = X[i2], a2i = X[i2 + 64];
    float a3r = X[i3], a3i = X[i3 + 64];
    float s0r = a0r + a2r, s0i = a0i + a2i;
    float s1r = a0r - a2r, s1i = a0i - a2i;
    float s2r = a1r + a3r, s2i = a1i + a3i;
    float s3r = a1r - a3r, s3i = a1i - a3i;
    dst[b]        = make_float2(s0r + s2r, s0i + s2i);
    dst[b + 512]  = make_float2(s1r - s3i, s1i + s3r);
    dst[b + 1024] = make_float2(s0r - s2r, s0i - s2i);
    dst[b + 1536] = make_float2(s1r + s3i, s1i - s3r);
  }
}

// Forward radix-4 final stage, plain, out-of-place (kfft path).
__device__ __forceinline__ void stage_r4_fwd(const float* X, float* Y) {
  const int t = (int)threadIdx.x;
  float O0r[4], O0i[4], O1r[4], O1i[4];
  bf4f(X, t, O0r, O0i);
  bf4f(X, t + 256, O1r, O1i);
#pragma unroll
  for (int m = 0; m < 4; ++m) {
    int i;
    i = WP(t + 512 * m);       Y[i] = O0r[m]; Y[i + 64] = O0i[m];
    i = WP(t + 256 + 512 * m); Y[i] = O1r[m]; Y[i + 64] = O1i[m];
  }
}

__device__ __forceinline__ void unpackX(float Pr, float Pi, float Qr, float Qi,
                                        int kk, float2& Xp, float2& Xq) {
  const float Er = 0.5f * (Pr + Qr), Ei = 0.5f * (Pi - Qi);
  const float Or = 0.5f * (Pi + Qi), Oi = 0.5f * (Qr - Pr);
  float sn, cs;
  sincos_rev((float)kk * INV_4096, sn, cs);
  Xp = make_float2(Er + cs * Or + sn * Oi, Ei + cs * Oi - sn * Or);
  Xq = make_float2(Er - cs * Or - sn * Oi, -Ei + cs * Oi - sn * Or);
}

__global__ __launch_bounds__(NT) void kfft_kernel(const float* __restrict__ kin,
                                                  float2* __restrict__ kf) {
  __shared__ float A_[4096];
  __shared__ float B_[4096];
  const int t = (int)threadIdx.x;
  const int h = (int)blockIdx.x;
  const float2* src = (const float2*)(kin + (size_t)h * 4096);
  int rd[8];
#pragma unroll
  for (int j = 0; j < 8; ++j) rd[j] = WP(t + 256 * j);
  stage1_global<-1>(src, A_);
  __syncthreads();
  stage_r8<-1, 8>(A_, B_, rd);
  __syncthreads();
  stage_r8<-1, 64>(B_, A_, rd);
  __syncthreads();
  stage_r4_fwd(A_, B_);
  __syncthreads();
  const float sc = 1.0f / 2048.0f;  // folded inverse-FFT normalization
  float2* kfrow = kf + (size_t)h * KF_LD;
#pragma unroll
  for (int u = 0; u < 4; ++u) {
    const int kk = t + 256 * u;  // 0..1023
    const int ip = WP(kk), iq = WP((2048 - kk) & 2047);
    float2 Xp, Xq;
    unpackX(B_[ip], B_[ip + 64], B_[iq], B_[iq + 64], kk, Xp, Xq);
    kfrow[kk] = make_float2(Xp.x * sc, Xp.y * sc);
    kfrow[2048 - kk] = make_float2(Xq.x * sc, Xq.y * sc);
  }
  if (t == 0) {
    const int ip = WP(1024);
    float2 Xp, Xq;
    unpackX(B_[ip], B_[ip + 64], B_[ip], B_[ip + 64], 1024, Xp, Xq);
    kfrow[1024] = make_float2(Xp.x * sc, Xp.y * sc);
  }
}

__global__ __launch_bounds__(NT) void conv_kernel(const float* __restrict__ x,
                                                  const float2* __restrict__ kf,
                                                  float* __restrict__ y, int H) {
  __shared__ float A_[4096];
  __shared__ float B_[4096];
  const int row = (int)blockIdx.x;
  const int h = row % H;
  const float2* src = (const float2*)(x + (size_t)row * 4096);
  float2* dst = (float2*)(y + (size_t)row * 4096);
  const float2* kfrow = kf + (size_t)h * KF_LD;
  const int t = (int)threadIdx.x;
  int rd[8];
#pragma unroll
  for (int j = 0; j < 8; ++j) rd[j] = WP(t + 256 * j);
  stage1_global<-1>(src, A_);        // fwd S=1 (r8), fused global load
  __syncthreads();
  stage_r8<-1, 8>(A_, B_, rd);       // fwd S=8
  __syncthreads();
  stage_r8<-1, 64>(B_, A_, rd);      // fwd S=64
  __syncthreads();
  fwd4_pw(A_, B_, kfrow);            // fwd S=512 (r4) + pointwise, fused
  __syncthreads();
  stage_r8<1, 1>(B_, A_, rd);        // inv S=1
  __syncthreads();
  stage_r8<1, 8>(A_, B_, rd);        // inv S=8
  __syncthreads();
  stage_r8<1, 64>(B_, A_, rd);       // inv S=64
  __syncthreads();
  inv4_store(A_, dst);               // inv S=512 (r4), fused global store
}

extern "C" void kernel_launch(void* const* d_in, const int* in_sizes, int n_in,
                              void* d_out, int out_size, void* d_ws, size_t ws_size,
                              hipStream_t stream) {
  const float* x = (const float*)d_in[0];
  const float* kin = (const float*)d_in[1];
  float* y = (float*)d_out;
  const int H = in_sizes[1] / 4096;    // 768
  const int BH = in_sizes[0] / 4096;   // 6144
  float2* kf = (float2*)d_ws;          // 768*2049*8B = 12.59 MB
  hipLaunchKernelGGL(kfft_kernel, dim3(H), dim3(NT), 0, stream, kin, kf);
  hipLaunchKernelGGL(conv_kernel, dim3(BH), dim3(NT), 0, stream, x, kf, y, H);
}

// Round 12
// 62.743 us; speedup vs baseline: 1.0495x; 1.0495x over previous
//
#include <hip/hip_runtime.h>
#include <math.h>

// FFT circular conv: y[b,h,:] = irfft(rfft(x[b,h,:]) * rfft(k[h,:])), N=4096.
// TWO-ROW SCHEME: rows r0,r1 share h (same kernel k). z = x[r0] + i*x[r1];
// IFFT(FFT_4096(z) * Kfull) = y[r0] + i*y[r1] (k real => no unpack needed).
// 4096 = 8^4: four radix-8 Stockham stages each way (S=1,8,64,512); final
// stages (S=512, p=0) twiddle-free; kf multiply fused into fwd final stage
// via mirror-conj read of the stored half-spectrum (ws stays 12.6 MB).
// LDS: ds_read2/write2-friendly [64 re|64 im] grouped layout + SW v2 swizzle
// (<=2-way on all patterns). Serial sincos twiddle chains, v_sin/v_cos in
// revolutions. 512-thread blocks, 64 KB LDS.

#define NT 512
#define KF_LD 2049
#define C_SQRT1_2 0.70710678118654752f
#define INV_4096 2.44140625e-4f

// Word swizzle (bijective involution, keyed on bits>=5).
#define SW(a) ((a) ^ (((a) >> 5) & 31) ^ (((a) >> 2) & 24))
// Point index -> LDS word index of re part (im at +64).
__device__ __forceinline__ int WP(int a) {
  const int s = SW(a);
  return 2 * s - (s & 63);
}

// sn = sin(2*pi*f), cs = cos(2*pi*f); f pre-reduced to [0,1).
__device__ __forceinline__ void sincos_rev(float f, float& sn, float& cs) {
  float s_, c_;
  asm("v_sin_f32 %0, %1" : "=v"(s_) : "v"(f));
  asm("v_cos_f32 %0, %1" : "=v"(c_) : "v"(f));
  sn = s_; cs = c_;
}

template <int SIGN>
__device__ __forceinline__ void bf8(const float ar[8], const float ai[8],
                                    float br[8], float bi[8]) {
  float s0r = ar[0] + ar[4], s0i = ai[0] + ai[4];
  float s1r = ar[0] - ar[4], s1i = ai[0] - ai[4];
  float s2r = ar[2] + ar[6], s2i = ai[2] + ai[6];
  float s3r = ar[2] - ar[6], s3i = ai[2] - ai[6];
  float E0r = s0r + s2r, E0i = s0i + s2i;
  float E2r = s0r - s2r, E2i = s0i - s2i;
  float E1r, E1i, E3r, E3i;
  if (SIGN < 0) { E1r = s1r + s3i; E1i = s1i - s3r; E3r = s1r - s3i; E3i = s1i + s3r; }
  else          { E1r = s1r - s3i; E1i = s1i + s3r; E3r = s1r + s3i; E3i = s1i - s3r; }
  float u0r = ar[1] + ar[5], u0i = ai[1] + ai[5];
  float u1r = ar[1] - ar[5], u1i = ai[1] - ai[5];
  float u2r = ar[3] + ar[7], u2i = ai[3] + ai[7];
  float u3r = ar[3] - ar[7], u3i = ai[3] - ai[7];
  float O0r = u0r + u2r, O0i = u0i + u2i;
  float O2r = u0r - u2r, O2i = u0i - u2i;
  float O1r, O1i, O3r, O3i;
  if (SIGN < 0) { O1r = u1r + u3i; O1i = u1i - u3r; O3r = u1r - u3i; O3i = u1i + u3r; }
  else          { O1r = u1r - u3i; O1i = u1i + u3r; O3r = u1r + u3i; O3i = u1i - u3r; }
  float t1r, t1i, t2r, t2i, t3r, t3i;
  if (SIGN < 0) {
    t1r = C_SQRT1_2 * (O1r + O1i); t1i = C_SQRT1_2 * (O1i - O1r);
    t2r = O2i;  t2i = -O2r;
    t3r = C_SQRT1_2 * (O3i - O3r); t3i = -C_SQRT1_2 * (O3r + O3i);
  } else {
    t1r = C_SQRT1_2 * (O1r - O1i); t1i = C_SQRT1_2 * (O1i + O1r);
    t2r = -O2i; t2i = O2r;
    t3r = -C_SQRT1_2 * (O3r + O3i); t3i = C_SQRT1_2 * (O3r - O3i);
  }
  br[0] = E0r + O0r; bi[0] = E0i + O0i;
  br[4] = E0r - O0r; bi[4] = E0i - O0i;
  br[1] = E1r + t1r; bi[1] = E1i + t1i;
  br[5] = E1r - t1r; bi[5] = E1i - t1i;
  br[2] = E2r + t2r; bi[2] = E2i + t2i;
  br[6] = E2r - t2r; bi[6] = E2i - t2i;
  br[3] = E3r + t3r; bi[3] = E3i + t3i;
  br[7] = E3r - t3r; bi[7] = E3i - t3i;
}

// Twiddled scatter-write: Y[ob+S*m] = b[m] * w^m, w = e^{SIGN*2*pi*i*f1}.
// Serial power chain (one live pair -> minimal VGPR).
template <int SIGN, int S>
__device__ __forceinline__ void tw_write(float* Y, int ob,
                                         const float br[8], const float bi[8],
                                         float f1) {
  { const int i0 = WP(ob); Y[i0] = br[0]; Y[i0 + 64] = bi[0]; }
  float sn, cs;
  sincos_rev(f1, sn, cs);
  const float w1r = cs, w1i = (SIGN > 0) ? sn : -sn;
  float cwr = w1r, cwi = w1i;
#pragma unroll
  for (int m = 1; m < 8; ++m) {
    const int idx = WP(ob + S * m);
    Y[idx] = br[m] * cwr - bi[m] * cwi;
    Y[idx + 64] = br[m] * cwi + bi[m] * cwr;
    if (m < 7) {
      const float nr = cwr * w1r - cwi * w1i;
      const float ni = cwr * w1i + cwi * w1r;
      cwr = nr; cwi = ni;
    }
  }
}

// Generic interior Stockham radix-8 stage (LDS -> LDS). N=4096, N/8=512.
template <int SIGN, int S>
__device__ __forceinline__ void stage_r8(const float* X, float* Y,
                                         const int rd[8]) {
  const int t = (int)threadIdx.x;
  const int q = t & (S - 1);
  const int p = t / S;
  float ar[8], ai[8];
#pragma unroll
  for (int j = 0; j < 8; ++j) {
    ar[j] = X[rd[j]];
    ai[j] = X[rd[j] + 64];
  }
  float br[8], bi[8];
  bf8<SIGN>(ar, ai, br, bi);
  tw_write<SIGN, S>(Y, q + 8 * S * p, br, bi, (float)(S * p) * INV_4096);
}

// Conv stage 1 (S=1): loads two real rows as z = x0 + i*x1, fused fwd bf8.
__device__ __forceinline__ void stage1_conv(const float* __restrict__ x0,
                                            const float* __restrict__ x1,
                                            float* Y) {
  const int t = (int)threadIdx.x;
  float ar[8], ai[8];
#pragma unroll
  for (int j = 0; j < 8; ++j) {
    ar[j] = x0[t + 512 * j];
    ai[j] = x1[t + 512 * j];
  }
  float br[8], bi[8];
  bf8<-1>(ar, ai, br, bi);
  tw_write<-1, 1>(Y, 8 * t, br, bi, (float)t * INV_4096);
}

// Conv fwd final stage (S=512, p=0 -> twiddle-free) + pointwise kf multiply.
// Kfull[k] = k<=2048 ? kf[k] : conj(kf[4096-k]).
__device__ __forceinline__ void stage4_kf(const float* X, float* Y,
                                          const float2* __restrict__ kfrow,
                                          const int rd[8]) {
  const int t = (int)threadIdx.x;
  float ar[8], ai[8];
#pragma unroll
  for (int j = 0; j < 8; ++j) {
    ar[j] = X[rd[j]];
    ai[j] = X[rd[j] + 64];
  }
  float br[8], bi[8];
  bf8<-1>(ar, ai, br, bi);
#pragma unroll
  for (int m = 0; m < 8; ++m) {
    const int k = t + 512 * m;
    float2 kv;
    if (m <= 3) {
      kv = kfrow[k];                    // k <= 2047
    } else {
      kv = kfrow[4096 - k];             // t==0,m==4 -> 2048 (Nyquist, ~real)
      kv.y = -kv.y;
    }
    const int i = WP(k);
    Y[i] = br[m] * kv.x - bi[m] * kv.y;
    Y[i + 64] = br[m] * kv.y + bi[m] * kv.x;
  }
}

// Inverse final stage (S=512, twiddle-free), store re->row0, im->row1.
__device__ __forceinline__ void stage4_store(const float* X,
                                             float* __restrict__ y0,
                                             float* __restrict__ y1,
                                             const int rd[8]) {
  const int t = (int)threadIdx.x;
  float ar[8], ai[8];
#pragma unroll
  for (int j = 0; j < 8; ++j) {
    ar[j] = X[rd[j]];
    ai[j] = X[rd[j] + 64];
  }
  float br[8], bi[8];
  bf8<1>(ar, ai, br, bi);
#pragma unroll
  for (int m = 0; m < 8; ++m) {
    const int k = t + 512 * m;
    y0[k] = br[m];
    y1[k] = bi[m];
  }
}

// kfft stage 1: real input (imag = 0), fused fwd bf8.
__device__ __forceinline__ void stage1_k(const float* __restrict__ kin,
                                         float* Y) {
  const int t = (int)threadIdx.x;
  float ar[8], ai[8];
#pragma unroll
  for (int j = 0; j < 8; ++j) {
    ar[j] = kin[t + 512 * j];
    ai[j] = 0.0f;
  }
  float br[8], bi[8];
  bf8<-1>(ar, ai, br, bi);
  tw_write<-1, 1>(Y, 8 * t, br, bi, (float)t * INV_4096);
}

// kfft final stage: store half spectrum [0..2048], 1/4096 scale folded.
__device__ __forceinline__ void stage4_kstore(const float* X,
                                              float2* __restrict__ kfrow,
                                              const int rd[8]) {
  const int t = (int)threadIdx.x;
  float ar[8], ai[8];
#pragma unroll
  for (int j = 0; j < 8; ++j) {
    ar[j] = X[rd[j]];
    ai[j] = X[rd[j] + 64];
  }
  float br[8], bi[8];
  bf8<-1>(ar, ai, br, bi);
  const float sc = 1.0f / 4096.0f;
#pragma unroll
  for (int m = 0; m < 4; ++m) {
    const int k = t + 512 * m;  // 0..2047
    kfrow[k] = make_float2(br[m] * sc, bi[m] * sc);
  }
  if (t == 0) kfrow[2048] = make_float2(br[4] * sc, bi[4] * sc);
}

__global__ __launch_bounds__(NT) void kfft_kernel(const float* __restrict__ kin,
                                                  float2* __restrict__ kf) {
  __shared__ float A_[8192];
  __shared__ float B_[8192];
  const int t = (int)threadIdx.x;
  const int h = (int)blockIdx.x;
  int rd[8];
#pragma unroll
  for (int j = 0; j < 8; ++j) rd[j] = WP(t + 512 * j);
  stage1_k(kin + (size_t)h * 4096, A_);
  __syncthreads();
  stage_r8<-1, 8>(A_, B_, rd);
  __syncthreads();
  stage_r8<-1, 64>(B_, A_, rd);
  __syncthreads();
  stage4_kstore(A_, kf + (size_t)h * KF_LD, rd);
}

__global__ __launch_bounds__(NT) void conv_kernel(const float* __restrict__ x,
                                                  const float2* __restrict__ kf,
                                                  float* __restrict__ y, int H) {
  __shared__ float A_[8192];
  __shared__ float B_[8192];
  const int bi = (int)blockIdx.x;
  const int h = bi % H;
  const int j = bi / H;                 // pair index 0..3 (B=8 -> 4 pairs)
  const size_t r0 = (size_t)(2 * j) * H + h;
  const size_t r1 = r0 + H;
  const float* src0 = x + r0 * 4096;
  const float* src1 = x + r1 * 4096;
  float* dst0 = y + r0 * 4096;
  float* dst1 = y + r1 * 4096;
  const float2* kfrow = kf + (size_t)h * KF_LD;
  const int t = (int)threadIdx.x;
  int rd[8];
#pragma unroll
  for (int jj = 0; jj < 8; ++jj) rd[jj] = WP(t + 512 * jj);
  stage1_conv(src0, src1, A_);       // fwd S=1, fused global load (2 rows)
  __syncthreads();
  stage_r8<-1, 8>(A_, B_, rd);       // fwd S=8
  __syncthreads();
  stage_r8<-1, 64>(B_, A_, rd);      // fwd S=64
  __syncthreads();
  stage4_kf(A_, B_, kfrow, rd);      // fwd S=512 (twiddle-free) * Kfull
  __syncthreads();
  stage_r8<1, 1>(B_, A_, rd);        // inv S=1
  __syncthreads();
  stage_r8<1, 8>(A_, B_, rd);        // inv S=8
  __syncthreads();
  stage_r8<1, 64>(B_, A_, rd);       // inv S=64
  __syncthreads();
  stage4_store(A_, dst0, dst1, rd);  // inv S=512, store re/im -> rows
}

extern "C" void kernel_launch(void* const* d_in, const int* in_sizes, int n_in,
                              void* d_out, int out_size, void* d_ws, size_t ws_size,
                              hipStream_t stream) {
  const float* x = (const float*)d_in[0];
  const float* kin = (const float*)d_in[1];
  float* y = (float*)d_out;
  const int H = in_sizes[1] / 4096;    // 768
  const int BH = in_sizes[0] / 4096;   // 6144 rows -> 3072 pairs
  float2* kf = (float2*)d_ws;          // 768*2049*8B = 12.59 MB
  hipLaunchKernelGGL(kfft_kernel, dim3(H), dim3(NT), 0, stream, kin, kf);
  hipLaunchKernelGGL(conv_kernel, dim3(BH / 2), dim3(NT), 0, stream, x, kf, y, H);
}